// Round 3
// baseline (444.417 us; speedup 1.0000x reference)
//
#include <hip/hip_runtime.h>
#include <hip/hip_bf16.h>

typedef unsigned short u16;
typedef __bf16 bf16x8 __attribute__((ext_vector_type(8)));
typedef float f32x4 __attribute__((ext_vector_type(4)));

// B=256, M=512, D=512, C=8, units 512/256/128, TEMP=0.5 (1/T = 2)
// Inputs: bf16 (harness-converted). Output: FLOAT32 (reference dtype):
// [z (8*256*128 f32) | losses (8 f32)].

__device__ __forceinline__ float bf2f(u16 u) {
    union { float f; unsigned int i; } x; x.i = ((unsigned int)u) << 16; return x.f;
}
__device__ __forceinline__ u16 f2bf(float f) {
    union { float f; unsigned int i; } x; x.f = f;
    unsigned int r = x.i + 0x7FFFu + ((x.i >> 16) & 1u);
    return (u16)(r >> 16);
}

// ---------------------------------------------------------------------------
// Masked sum-pool: one block per b. pooled[b][d] = sum_m (mask[b][m]==0) ec[b][m][d]
// ---------------------------------------------------------------------------
__global__ __launch_bounds__(256) void pool_kernel(
    const u16* __restrict__ ec, const u16* __restrict__ mask,
    u16* __restrict__ pooled)
{
    int b = blockIdx.x, tid = threadIdx.x;
    __shared__ float wm[512];
    __shared__ float red[4][512];
    for (int i = 0; i < 2; i++) {
        int m = tid + i * 256;
        wm[m] = (bf2f(mask[b * 512 + m]) == 0.0f) ? 1.0f : 0.0f;  // keep when mask==0
    }
    __syncthreads();
    int g = tid & 63, mo = tid >> 6;   // wave mo handles m % 4 == mo (wave-uniform branch)
    float acc[8];
    #pragma unroll
    for (int j = 0; j < 8; j++) acc[j] = 0.0f;
    const u16* base = ec + (size_t)b * 512 * 512;
    for (int m = mo; m < 512; m += 4) {
        if (wm[m] != 0.0f) {
            union { uint4 v; u16 s[8]; } u;
            u.v = *(const uint4*)&base[(size_t)m * 512 + g * 8];
            #pragma unroll
            for (int j = 0; j < 8; j++) acc[j] += bf2f(u.s[j]);
        }
    }
    #pragma unroll
    for (int j = 0; j < 8; j++) red[mo][g * 8 + j] = acc[j];
    __syncthreads();
    for (int i = 0; i < 2; i++) {
        int d = tid + i * 256;
        float s = red[0][d] + red[1][d] + red[2][d] + red[3][d];
        pooled[(size_t)b * 512 + d] = f2bf(s);
    }
}

// ---------------------------------------------------------------------------
// 64x64-tile bf16 GEMM + bias + relu -> bf16, transposing W in the LDS stage.
// A: [256 x K] row-major (per-class stride aBatch), W: [c][K][N] row-major,
// out: [c][256][N]. 4 waves, wave = 16 rows x 64 cols, BK=64.
// ---------------------------------------------------------------------------
__global__ __launch_bounds__(256) void mlp_gemm64(
    const u16* __restrict__ A, const u16* __restrict__ W,
    const u16* __restrict__ bias, u16* __restrict__ out,
    int K, int N, int aBatch, int mtiles, int ntiles)
{
    int bid = blockIdx.x;
    int per_c = mtiles * ntiles;
    int c = bid / per_c, rem = bid % per_c;
    int mt = rem / ntiles, nt = rem % ntiles;
    const u16* aBase = A + (size_t)c * aBatch + (size_t)mt * 64 * K;
    const u16* wBase = W + (size_t)c * K * N + nt * 64;   // + k*N later
    __shared__ __align__(16) u16 As[64][72];
    __shared__ __align__(16) u16 Bs[64][72];   // [n][k]
    int tid = threadIdx.x;
    int w = tid >> 6, l15 = tid & 15, q = (tid >> 4) & 3;
    f32x4 acc[4];
    #pragma unroll
    for (int t = 0; t < 4; t++)
        #pragma unroll
        for (int e = 0; e < 4; e++) acc[t][e] = 0.0f;

    for (int k0 = 0; k0 < K; k0 += 64) {
        #pragma unroll
        for (int i = 0; i < 2; i++) {
            int idx = tid + i * 256;
            int r = idx >> 3, kc = idx & 7;                 // A: row r, k-chunk kc
            *(uint4*)&As[r][kc * 8] = *(const uint4*)&aBase[(size_t)r * K + k0 + kc * 8];
            int kk = idx >> 3, n8 = (idx & 7) * 8;          // W: row kk, 8 n's
            union { uint4 v; u16 s[8]; } u;
            u.v = *(const uint4*)&wBase[(size_t)(k0 + kk) * N + n8];
            #pragma unroll
            for (int j = 0; j < 8; j++) Bs[n8 + j][kk] = u.s[j];
        }
        __syncthreads();
        #pragma unroll
        for (int ks = 0; ks < 64; ks += 32) {
            bf16x8 av = *(const bf16x8*)&As[w * 16 + l15][ks + q * 8];
            #pragma unroll
            for (int t = 0; t < 4; t++) {
                bf16x8 bv = *(const bf16x8*)&Bs[t * 16 + l15][ks + q * 8];
                acc[t] = __builtin_amdgcn_mfma_f32_16x16x32_bf16(av, bv, acc[t], 0, 0, 0);
            }
        }
        __syncthreads();
    }
    #pragma unroll
    for (int t = 0; t < 4; t++) {
        int col = nt * 64 + t * 16 + l15;
        float bv = bf2f(bias[c * N + col]);
        #pragma unroll
        for (int r = 0; r < 4; r++) {
            int row = mt * 64 + w * 16 + q * 4 + r;
            float v = acc[t][r] + bv;
            v = v > 0.0f ? v : 0.0f;
            out[((size_t)c * 256 + row) * N + col] = f2bf(v);
        }
    }
}

// ---------------------------------------------------------------------------
// Layer 3 (K=256, N=128 full) + fused L2 normalize; W3: [c][256][128].
// Writes z as FLOAT32 to d_out and bf16 copy to ws for the contrast kernel.
// ---------------------------------------------------------------------------
__global__ __launch_bounds__(256) void mlp_gemm3_norm(
    const u16* __restrict__ A, const u16* __restrict__ W,
    const u16* __restrict__ bias, float* __restrict__ zout, u16* __restrict__ zbf)
{
    const int K = 256, N = 128;
    int bid = blockIdx.x;
    int c = bid >> 2, mt = bid & 3;
    const u16* aBase = A + ((size_t)c * 256 + mt * 64) * K;
    const u16* wBase = W + (size_t)c * K * N;
    __shared__ __align__(16) u16 As[64][72];
    __shared__ __align__(16) u16 Bs[128][72];   // [n][k]
    int tid = threadIdx.x;
    int w = tid >> 6, l15 = tid & 15, q = (tid >> 4) & 3;
    f32x4 acc[8];
    #pragma unroll
    for (int t = 0; t < 8; t++)
        #pragma unroll
        for (int e = 0; e < 4; e++) acc[t][e] = 0.0f;

    for (int k0 = 0; k0 < K; k0 += 64) {
        #pragma unroll
        for (int i = 0; i < 2; i++) {
            int idx = tid + i * 256; int r = idx >> 3, kc = idx & 7;
            *(uint4*)&As[r][kc * 8] = *(const uint4*)&aBase[(size_t)r * K + k0 + kc * 8];
        }
        #pragma unroll
        for (int i = 0; i < 4; i++) {
            int idx = tid + i * 256;
            int kk = idx >> 4, n8 = (idx & 15) * 8;
            union { uint4 v; u16 s[8]; } u;
            u.v = *(const uint4*)&wBase[(size_t)(k0 + kk) * N + n8];
            #pragma unroll
            for (int j = 0; j < 8; j++) Bs[n8 + j][kk] = u.s[j];
        }
        __syncthreads();
        #pragma unroll
        for (int ks = 0; ks < 64; ks += 32) {
            bf16x8 av = *(const bf16x8*)&As[w * 16 + l15][ks + q * 8];
            #pragma unroll
            for (int t = 0; t < 8; t++) {
                bf16x8 bv = *(const bf16x8*)&Bs[t * 16 + l15][ks + q * 8];
                acc[t] = __builtin_amdgcn_mfma_f32_16x16x32_bf16(av, bv, acc[t], 0, 0, 0);
            }
        }
        __syncthreads();
    }
    float val[8][4];
    float ssq[4] = {0.f, 0.f, 0.f, 0.f};
    #pragma unroll
    for (int t = 0; t < 8; t++) {
        float bv = bf2f(bias[c * N + t * 16 + l15]);
        #pragma unroll
        for (int r = 0; r < 4; r++) {
            float v = acc[t][r] + bv;
            v = v > 0.0f ? v : 0.0f;
            val[t][r] = v;
            ssq[r] += v * v;
        }
    }
    #pragma unroll
    for (int off = 1; off < 16; off <<= 1)
        #pragma unroll
        for (int r = 0; r < 4; r++) ssq[r] += __shfl_xor(ssq[r], off);
    float sc[4];
    #pragma unroll
    for (int r = 0; r < 4; r++) sc[r] = rsqrtf(fmaxf(ssq[r], 1e-12f));
    #pragma unroll
    for (int t = 0; t < 8; t++)
        #pragma unroll
        for (int r = 0; r < 4; r++) {
            int row = mt * 64 + w * 16 + q * 4 + r;
            int col = t * 16 + l15;
            float zv = val[t][r] * sc[r];
            size_t o = ((size_t)c * 256 + row) * 128 + col;
            zout[o] = zv;
            zbf[o] = f2bf(zv);
        }
}

// ---------------------------------------------------------------------------
// Contrastive partials: per (c, b-tile, k-tile) 64x64 block of ip = (z z^T)/T
// with zeroed diagonal; accumulate per-row sum exp(ip), sum ip*mask1, mask0.
// ---------------------------------------------------------------------------
__global__ __launch_bounds__(256) void contrast_partial(
    const u16* __restrict__ z, const int* __restrict__ label,
    float* __restrict__ rws, float* __restrict__ s1ws, float* __restrict__ s0ws)
{
    int bid = blockIdx.x;
    int c = bid >> 4, rem = bid & 15;
    int bt = rem >> 2, kt = rem & 3;
    __shared__ __align__(16) u16 Zb[64][136];
    __shared__ __align__(16) u16 Zk[64][136];
    __shared__ float lm1[64];
    int tid = threadIdx.x;
    int w = tid >> 6, l15 = tid & 15, q = (tid >> 4) & 3;
    const u16* zc = z + (size_t)c * 256 * 128;
    #pragma unroll
    for (int i = 0; i < 4; i++) {
        int idx = tid + i * 256; int r = idx >> 4, kc = idx & 15;
        *(uint4*)&Zb[r][kc * 8] = *(const uint4*)&zc[(size_t)(bt * 64 + r) * 128 + kc * 8];
        *(uint4*)&Zk[r][kc * 8] = *(const uint4*)&zc[(size_t)(kt * 64 + r) * 128 + kc * 8];
    }
    if (tid < 64) lm1[tid] = (label[(kt * 64 + tid) * 8 + c] == 1) ? 1.0f : 0.0f;
    __syncthreads();

    f32x4 acc[4];
    #pragma unroll
    for (int t = 0; t < 4; t++)
        #pragma unroll
        for (int e = 0; e < 4; e++) acc[t][e] = 0.0f;
    #pragma unroll
    for (int ks = 0; ks < 128; ks += 32) {
        bf16x8 av = *(const bf16x8*)&Zb[w * 16 + l15][ks + q * 8];
        #pragma unroll
        for (int t = 0; t < 4; t++) {
            bf16x8 bv = *(const bf16x8*)&Zk[t * 16 + l15][ks + q * 8];
            acc[t] = __builtin_amdgcn_mfma_f32_16x16x32_bf16(av, bv, acc[t], 0, 0, 0);
        }
    }
    float pr[4] = {0.f,0.f,0.f,0.f}, p1[4] = {0.f,0.f,0.f,0.f}, p0[4] = {0.f,0.f,0.f,0.f};
    #pragma unroll
    for (int t = 0; t < 4; t++) {
        int kl = t * 16 + l15;
        int kkg = kt * 64 + kl;
        float m1 = lm1[kl];
        #pragma unroll
        for (int r = 0; r < 4; r++) {
            int rbg = bt * 64 + w * 16 + q * 4 + r;
            float v = (rbg == kkg) ? 0.0f : acc[t][r] * 2.0f;  // /TEMP, zero diag
            pr[r] += __expf(v);
            p1[r] += v * m1;
            p0[r] += v * (1.0f - m1);
        }
    }
    #pragma unroll
    for (int off = 1; off < 16; off <<= 1)
        #pragma unroll
        for (int r = 0; r < 4; r++) {
            pr[r] += __shfl_xor(pr[r], off);
            p1[r] += __shfl_xor(p1[r], off);
            p0[r] += __shfl_xor(p0[r], off);
        }
    if (l15 == 0) {
        #pragma unroll
        for (int r = 0; r < 4; r++) {
            int rbg = bt * 64 + w * 16 + q * 4 + r;
            atomicAdd(&rws[c * 256 + rbg], pr[r]);
            atomicAdd(&s1ws[c * 256 + rbg], p1[r]);
            atomicAdd(&s0ws[c * 256 + rbg], p0[r]);
        }
    }
}

// ---------------------------------------------------------------------------
// Final per-class loss (float32 out). losses[c] = -sum_b (numer/num_vec - log r).
// ---------------------------------------------------------------------------
__global__ __launch_bounds__(256) void loss_kernel(
    const int* __restrict__ label, const float* __restrict__ rws,
    const float* __restrict__ s1ws, const float* __restrict__ s0ws,
    float* __restrict__ lout)
{
    int c = blockIdx.x, b = threadIdx.x;
    __shared__ float sh[256];
    int lab = label[b * 8 + c];
    float m1 = (lab == 1) ? 1.0f : 0.0f;
    sh[b] = m1;
    __syncthreads();
    for (int s = 128; s > 0; s >>= 1) {
        if (b < s) sh[b] += sh[b + s];
        __syncthreads();
    }
    float num_p = sh[0];
    __syncthreads();
    float num_n = 256.0f - num_p;
    float num_vec = (m1 > 0.0f) ? num_p : num_n;
    float numer = (m1 > 0.0f) ? s1ws[c * 256 + b] : s0ws[c * 256 + b];
    float term = numer / num_vec - __logf(rws[c * 256 + b]);
    sh[b] = term;
    __syncthreads();
    for (int s = 128; s > 0; s >>= 1) {
        if (b < s) sh[b] += sh[b + s];
        __syncthreads();
    }
    if (b == 0) lout[c] = -sh[0];
}

// ---------------------------------------------------------------------------
extern "C" void kernel_launch(void* const* d_in, const int* in_sizes, int n_in,
                              void* d_out, int out_size, void* d_ws, size_t ws_size,
                              hipStream_t stream) {
    (void)in_sizes; (void)n_in; (void)ws_size;
    const u16* ec   = (const u16*)d_in[0];
    const u16* mask = (const u16*)d_in[1];
    const int* label = (const int*)d_in[2];
    const u16* W1 = (const u16*)d_in[3];
    const u16* b1 = (const u16*)d_in[4];
    const u16* W2 = (const u16*)d_in[5];
    const u16* b2 = (const u16*)d_in[6];
    const u16* W3 = (const u16*)d_in[7];
    const u16* b3 = (const u16*)d_in[8];
    float* zout = (float*)d_out;                 // fp32 output: z then losses
    char* ws = (char*)d_ws;
    // workspace layout (bytes) — total 3,956,736 B (~3.8 MB)
    u16* pooled = (u16*)(ws + 0);          // 256*512*2   =   262,144
    u16* h1     = (u16*)(ws + 262144);     // 8*256*512*2 = 2,097,152
    u16* h2     = (u16*)(ws + 2359296);    // 8*256*256*2 = 1,048,576
    u16* zbf    = (u16*)(ws + 3407872);    // 8*256*128*2 =   524,288
    float* rws  = (float*)(ws + 3932160);  // 3 * 2048 * 4 =  24,576
    float* s1ws = rws + 2048;
    float* s0ws = rws + 4096;

    hipMemsetAsync(rws, 0, 3 * 2048 * sizeof(float), stream);
    pool_kernel<<<256, 256, 0, stream>>>(ec, mask, pooled);
    mlp_gemm64<<<256, 256, 0, stream>>>(pooled, W1, b1, h1, 512, 512, 0, 4, 8);
    mlp_gemm64<<<128, 256, 0, stream>>>(h1, W2, b2, h2, 512, 256, 256 * 512, 4, 4);
    mlp_gemm3_norm<<<32, 256, 0, stream>>>(h2, W3, b3, zout, zbf);
    contrast_partial<<<128, 256, 0, stream>>>(zbf, label, rws, s1ws, s0ws);
    loss_kernel<<<8, 256, 0, stream>>>(label, rws, s1ws, s0ws, zout + (out_size - 8));
}

// Round 4
// 384.836 us; speedup vs baseline: 1.1548x; 1.1548x over previous
//
#include <hip/hip_runtime.h>
#include <hip/hip_bf16.h>

typedef unsigned short u16;
typedef __bf16 bf16x8 __attribute__((ext_vector_type(8)));
typedef float f32x4 __attribute__((ext_vector_type(4)));

// B=256, M=512, D=512, C=8, units 512/256/128, TEMP=0.5 (1/T = 2)
// Inputs: bf16. Output: FLOAT32: [z (8*256*128) | losses (8)].

__device__ __forceinline__ float bf2f(u16 u) {
    union { float f; unsigned int i; } x; x.i = ((unsigned int)u) << 16; return x.f;
}
__device__ __forceinline__ u16 f2bf(float f) {
    union { float f; unsigned int i; } x; x.f = f;
    unsigned int r = x.i + 0x7FFFu + ((x.i >> 16) & 1u);
    return (u16)(r >> 16);
}

// ---------------------------------------------------------------------------
// Masked sum-pool, 1024 threads (16 waves) per block, one block per b.
// ---------------------------------------------------------------------------
__global__ __launch_bounds__(1024) void pool_kernel(
    const u16* __restrict__ ec, const u16* __restrict__ mask,
    u16* __restrict__ pooled)
{
    int b = blockIdx.x, tid = threadIdx.x;
    __shared__ float wm[512];
    __shared__ float red[16][512];   // 32 KB
    if (tid < 512)
        wm[tid] = (bf2f(mask[b * 512 + tid]) == 0.0f) ? 1.0f : 0.0f;  // keep when mask==0
    __syncthreads();
    int g = tid & 63, mo = tid >> 6;   // wave mo handles m % 16 == mo (wave-uniform branch)
    float acc[8];
    #pragma unroll
    for (int j = 0; j < 8; j++) acc[j] = 0.0f;
    const u16* base = ec + (size_t)b * 512 * 512;
    for (int m = mo; m < 512; m += 16) {
        if (wm[m] != 0.0f) {
            union { uint4 v; u16 s[8]; } u;
            u.v = *(const uint4*)&base[(size_t)m * 512 + g * 8];
            #pragma unroll
            for (int j = 0; j < 8; j++) acc[j] += bf2f(u.s[j]);
        }
    }
    #pragma unroll
    for (int j = 0; j < 8; j++) red[mo][g * 8 + j] = acc[j];
    __syncthreads();
    if (tid < 512) {
        float s = 0.0f;
        #pragma unroll
        for (int k = 0; k < 16; k++) s += red[k][tid];
        pooled[(size_t)b * 512 + tid] = f2bf(s);
    }
}

// ---------------------------------------------------------------------------
// 64x64-tile bf16 GEMM + bias + relu -> bf16, W transposed during LDS stage,
// double-buffered LDS + register prefetch (one barrier per K-iter).
// A: [256 x K] rm (per-class stride aBatch), W: [c][K][N] rm, out: [c][256][N].
// ---------------------------------------------------------------------------
__global__ __launch_bounds__(256) void mlp_gemm64(
    const u16* __restrict__ A, const u16* __restrict__ W,
    const u16* __restrict__ bias, u16* __restrict__ out,
    int K, int N, int aBatch, int mtiles, int ntiles)
{
    int bid = blockIdx.x;
    int per_c = mtiles * ntiles;
    int c = bid / per_c, rem = bid % per_c;
    int mt = rem / ntiles, nt = rem % ntiles;
    const u16* aBase = A + (size_t)c * aBatch + (size_t)mt * 64 * K;
    const u16* wBase = W + (size_t)c * K * N + nt * 64;
    __shared__ __align__(16) u16 As[2][64][72];
    __shared__ __align__(16) u16 Bs[2][64][72];   // [n][k]
    int tid = threadIdx.x;
    int w = tid >> 6, l15 = tid & 15, q = (tid >> 4) & 3;
    // per-thread staging coords (2 rounds of 256 threads)
    int r0 = tid >> 3, kc0 = tid & 7;            // round 0: idx = tid
    int r1 = (tid + 256) >> 3, kc1 = tid & 7;    // round 1
    f32x4 acc[4];
    #pragma unroll
    for (int t = 0; t < 4; t++)
        #pragma unroll
        for (int e = 0; e < 4; e++) acc[t][e] = 0.0f;

    uint4 aReg[2], wReg[2];
    // prologue: load k0 = 0
    aReg[0] = *(const uint4*)&aBase[(size_t)r0 * K + kc0 * 8];
    aReg[1] = *(const uint4*)&aBase[(size_t)r1 * K + kc1 * 8];
    wReg[0] = *(const uint4*)&wBase[(size_t)r0 * N + kc0 * 8];
    wReg[1] = *(const uint4*)&wBase[(size_t)r1 * N + kc1 * 8];

    int nIter = K >> 6;
    for (int it = 0; it < nIter; ++it) {
        int cur = it & 1;
        // commit staged regs to LDS buffer `cur` (B transposed: scatter u16)
        *(uint4*)&As[cur][r0][kc0 * 8] = aReg[0];
        *(uint4*)&As[cur][r1][kc1 * 8] = aReg[1];
        {
            union { uint4 v; u16 s[8]; } u; u.v = wReg[0];
            #pragma unroll
            for (int j = 0; j < 8; j++) Bs[cur][kc0 * 8 + j][r0] = u.s[j];
        }
        {
            union { uint4 v; u16 s[8]; } u; u.v = wReg[1];
            #pragma unroll
            for (int j = 0; j < 8; j++) Bs[cur][kc1 * 8 + j][r1] = u.s[j];
        }
        // issue next-iter global loads (overlap with barrier + MFMA below)
        if (it + 1 < nIter) {
            int k0n = (it + 1) * 64;
            aReg[0] = *(const uint4*)&aBase[(size_t)r0 * K + k0n + kc0 * 8];
            aReg[1] = *(const uint4*)&aBase[(size_t)r1 * K + k0n + kc1 * 8];
            wReg[0] = *(const uint4*)&wBase[(size_t)(k0n + r0) * N + kc0 * 8];
            wReg[1] = *(const uint4*)&wBase[(size_t)(k0n + r1) * N + kc1 * 8];
        }
        __syncthreads();
        #pragma unroll
        for (int ks = 0; ks < 64; ks += 32) {
            bf16x8 av = *(const bf16x8*)&As[cur][w * 16 + l15][ks + q * 8];
            #pragma unroll
            for (int t = 0; t < 4; t++) {
                bf16x8 bv = *(const bf16x8*)&Bs[cur][t * 16 + l15][ks + q * 8];
                acc[t] = __builtin_amdgcn_mfma_f32_16x16x32_bf16(av, bv, acc[t], 0, 0, 0);
            }
        }
        // no end barrier needed: next iter writes the OTHER buffer; the single
        // barrier above separates those writes from this buffer's prior readers.
    }
    #pragma unroll
    for (int t = 0; t < 4; t++) {
        int col = nt * 64 + t * 16 + l15;
        float bv = bf2f(bias[c * N + col]);
        #pragma unroll
        for (int r = 0; r < 4; r++) {
            int row = mt * 64 + w * 16 + q * 4 + r;
            float v = acc[t][r] + bv;
            v = v > 0.0f ? v : 0.0f;
            out[((size_t)c * 256 + row) * N + col] = f2bf(v);
        }
    }
}

// ---------------------------------------------------------------------------
// Layer 3 (K=256, N=128) + fused L2 normalize. 128 blocks: (c, 16-row tile).
// 4 waves; wave w covers cols w*32..w*32+31, all 16 rows. Cross-wave ssq via LDS.
// ---------------------------------------------------------------------------
__global__ __launch_bounds__(256) void mlp_gemm3_norm(
    const u16* __restrict__ A, const u16* __restrict__ W,
    const u16* __restrict__ bias, float* __restrict__ zout, u16* __restrict__ zbf)
{
    const int K = 256, N = 128;
    int bid = blockIdx.x;
    int c = bid >> 4, mt = bid & 15;
    const u16* aBase = A + ((size_t)c * 256 + mt * 16) * K;
    const u16* wBase = W + (size_t)c * K * N;
    __shared__ __align__(16) u16 As[16][72];
    __shared__ __align__(16) u16 Bs[128][72];   // [n][k]
    __shared__ float ssq_s[4][16];
    __shared__ float scale_s[16];
    int tid = threadIdx.x;
    int w = tid >> 6, l15 = tid & 15, q = (tid >> 4) & 3;
    f32x4 acc[2];
    #pragma unroll
    for (int t = 0; t < 2; t++)
        #pragma unroll
        for (int e = 0; e < 4; e++) acc[t][e] = 0.0f;

    for (int k0 = 0; k0 < K; k0 += 64) {
        if (tid < 128) {
            int r = tid >> 3, kc = tid & 7;
            *(uint4*)&As[r][kc * 8] = *(const uint4*)&aBase[(size_t)r * K + k0 + kc * 8];
        }
        #pragma unroll
        for (int i = 0; i < 4; i++) {
            int idx = tid + i * 256;
            int kk = idx >> 4, n8 = (idx & 15) * 8;
            union { uint4 v; u16 s[8]; } u;
            u.v = *(const uint4*)&wBase[(size_t)(k0 + kk) * N + n8];
            #pragma unroll
            for (int j = 0; j < 8; j++) Bs[n8 + j][kk] = u.s[j];
        }
        __syncthreads();
        #pragma unroll
        for (int ks = 0; ks < 64; ks += 32) {
            bf16x8 av = *(const bf16x8*)&As[l15][ks + q * 8];
            #pragma unroll
            for (int t = 0; t < 2; t++) {
                bf16x8 bv = *(const bf16x8*)&Bs[w * 32 + t * 16 + l15][ks + q * 8];
                acc[t] = __builtin_amdgcn_mfma_f32_16x16x32_bf16(av, bv, acc[t], 0, 0, 0);
            }
        }
        __syncthreads();
    }
    // epilogue: bias + relu, per-row sum of squares across the full 128 cols
    float val[2][4];
    float ssq[4] = {0.f, 0.f, 0.f, 0.f};
    #pragma unroll
    for (int t = 0; t < 2; t++) {
        float bv = bf2f(bias[c * N + w * 32 + t * 16 + l15]);
        #pragma unroll
        for (int r = 0; r < 4; r++) {
            float v = acc[t][r] + bv;
            v = v > 0.0f ? v : 0.0f;
            val[t][r] = v;
            ssq[r] += v * v;
        }
    }
    #pragma unroll
    for (int off = 1; off < 16; off <<= 1)
        #pragma unroll
        for (int r = 0; r < 4; r++) ssq[r] += __shfl_xor(ssq[r], off);
    if (l15 == 0) {
        #pragma unroll
        for (int r = 0; r < 4; r++) ssq_s[w][q * 4 + r] = ssq[r];
    }
    __syncthreads();
    if (tid < 16) {
        float s = ssq_s[0][tid] + ssq_s[1][tid] + ssq_s[2][tid] + ssq_s[3][tid];
        scale_s[tid] = rsqrtf(fmaxf(s, 1e-12f));
    }
    __syncthreads();
    #pragma unroll
    for (int t = 0; t < 2; t++)
        #pragma unroll
        for (int r = 0; r < 4; r++) {
            int row = mt * 16 + q * 4 + r;
            int col = w * 32 + t * 16 + l15;
            float zv = val[t][r] * scale_s[q * 4 + r];
            size_t o = ((size_t)c * 256 + row) * 128 + col;
            zout[o] = zv;
            zbf[o] = f2bf(zv);
        }
}

// ---------------------------------------------------------------------------
// Contrastive partials: per (c, b-tile, k-tile) 64x64 block of ip = (z z^T)/T
// with zeroed diagonal; accumulate per-row sum exp(ip), sum ip*mask1, mask0.
// ---------------------------------------------------------------------------
__global__ __launch_bounds__(256) void contrast_partial(
    const u16* __restrict__ z, const int* __restrict__ label,
    float* __restrict__ rws, float* __restrict__ s1ws, float* __restrict__ s0ws)
{
    int bid = blockIdx.x;
    int c = bid >> 4, rem = bid & 15;
    int bt = rem >> 2, kt = rem & 3;
    __shared__ __align__(16) u16 Zb[64][136];
    __shared__ __align__(16) u16 Zk[64][136];
    __shared__ float lm1[64];
    int tid = threadIdx.x;
    int w = tid >> 6, l15 = tid & 15, q = (tid >> 4) & 3;
    const u16* zc = z + (size_t)c * 256 * 128;
    #pragma unroll
    for (int i = 0; i < 4; i++) {
        int idx = tid + i * 256; int r = idx >> 4, kc = idx & 15;
        *(uint4*)&Zb[r][kc * 8] = *(const uint4*)&zc[(size_t)(bt * 64 + r) * 128 + kc * 8];
        *(uint4*)&Zk[r][kc * 8] = *(const uint4*)&zc[(size_t)(kt * 64 + r) * 128 + kc * 8];
    }
    if (tid < 64) lm1[tid] = (label[(kt * 64 + tid) * 8 + c] == 1) ? 1.0f : 0.0f;
    __syncthreads();

    f32x4 acc[4];
    #pragma unroll
    for (int t = 0; t < 4; t++)
        #pragma unroll
        for (int e = 0; e < 4; e++) acc[t][e] = 0.0f;
    #pragma unroll
    for (int ks = 0; ks < 128; ks += 32) {
        bf16x8 av = *(const bf16x8*)&Zb[w * 16 + l15][ks + q * 8];
        #pragma unroll
        for (int t = 0; t < 4; t++) {
            bf16x8 bv = *(const bf16x8*)&Zk[t * 16 + l15][ks + q * 8];
            acc[t] = __builtin_amdgcn_mfma_f32_16x16x32_bf16(av, bv, acc[t], 0, 0, 0);
        }
    }
    float pr[4] = {0.f,0.f,0.f,0.f}, p1[4] = {0.f,0.f,0.f,0.f}, p0[4] = {0.f,0.f,0.f,0.f};
    #pragma unroll
    for (int t = 0; t < 4; t++) {
        int kl = t * 16 + l15;
        int kkg = kt * 64 + kl;
        float m1 = lm1[kl];
        #pragma unroll
        for (int r = 0; r < 4; r++) {
            int rbg = bt * 64 + w * 16 + q * 4 + r;
            float v = (rbg == kkg) ? 0.0f : acc[t][r] * 2.0f;  // /TEMP, zero diag
            pr[r] += __expf(v);
            p1[r] += v * m1;
            p0[r] += v * (1.0f - m1);
        }
    }
    #pragma unroll
    for (int off = 1; off < 16; off <<= 1)
        #pragma unroll
        for (int r = 0; r < 4; r++) {
            pr[r] += __shfl_xor(pr[r], off);
            p1[r] += __shfl_xor(p1[r], off);
            p0[r] += __shfl_xor(p0[r], off);
        }
    if (l15 == 0) {
        #pragma unroll
        for (int r = 0; r < 4; r++) {
            int rbg = bt * 64 + w * 16 + q * 4 + r;
            atomicAdd(&rws[c * 256 + rbg], pr[r]);
            atomicAdd(&s1ws[c * 256 + rbg], p1[r]);
            atomicAdd(&s0ws[c * 256 + rbg], p0[r]);
        }
    }
}

// ---------------------------------------------------------------------------
// Final per-class loss (float32 out). losses[c] = -sum_b (numer/num_vec - log r).
// ---------------------------------------------------------------------------
__global__ __launch_bounds__(256) void loss_kernel(
    const int* __restrict__ label, const float* __restrict__ rws,
    const float* __restrict__ s1ws, const float* __restrict__ s0ws,
    float* __restrict__ lout)
{
    int c = blockIdx.x, b = threadIdx.x;
    __shared__ float sh[256];
    int lab = label[b * 8 + c];
    float m1 = (lab == 1) ? 1.0f : 0.0f;
    sh[b] = m1;
    __syncthreads();
    for (int s = 128; s > 0; s >>= 1) {
        if (b < s) sh[b] += sh[b + s];
        __syncthreads();
    }
    float num_p = sh[0];
    __syncthreads();
    float num_n = 256.0f - num_p;
    float num_vec = (m1 > 0.0f) ? num_p : num_n;
    float numer = (m1 > 0.0f) ? s1ws[c * 256 + b] : s0ws[c * 256 + b];
    float term = numer / num_vec - __logf(rws[c * 256 + b]);
    sh[b] = term;
    __syncthreads();
    for (int s = 128; s > 0; s >>= 1) {
        if (b < s) sh[b] += sh[b + s];
        __syncthreads();
    }
    if (b == 0) lout[c] = -sh[0];
}

// ---------------------------------------------------------------------------
extern "C" void kernel_launch(void* const* d_in, const int* in_sizes, int n_in,
                              void* d_out, int out_size, void* d_ws, size_t ws_size,
                              hipStream_t stream) {
    (void)in_sizes; (void)n_in; (void)ws_size;
    const u16* ec   = (const u16*)d_in[0];
    const u16* mask = (const u16*)d_in[1];
    const int* label = (const int*)d_in[2];
    const u16* W1 = (const u16*)d_in[3];
    const u16* b1 = (const u16*)d_in[4];
    const u16* W2 = (const u16*)d_in[5];
    const u16* b2 = (const u16*)d_in[6];
    const u16* W3 = (const u16*)d_in[7];
    const u16* b3 = (const u16*)d_in[8];
    float* zout = (float*)d_out;                 // fp32 output: z then losses
    char* ws = (char*)d_ws;
    // workspace layout (bytes) — total ~3.9 MB
    u16* pooled = (u16*)(ws + 0);          // 256*512*2   =   262,144
    u16* h1     = (u16*)(ws + 262144);     // 8*256*512*2 = 2,097,152
    u16* h2     = (u16*)(ws + 2359296);    // 8*256*256*2 = 1,048,576
    u16* zbf    = (u16*)(ws + 3407872);    // 8*256*128*2 =   524,288
    float* rws  = (float*)(ws + 3932160);  // 3 * 2048 * 4 =  24,576
    float* s1ws = rws + 2048;
    float* s0ws = rws + 4096;

    hipMemsetAsync(rws, 0, 3 * 2048 * sizeof(float), stream);
    pool_kernel<<<256, 1024, 0, stream>>>(ec, mask, pooled);
    mlp_gemm64<<<256, 256, 0, stream>>>(pooled, W1, b1, h1, 512, 512, 0, 4, 8);
    mlp_gemm64<<<128, 256, 0, stream>>>(h1, W2, b2, h2, 512, 256, 256 * 512, 4, 4);
    mlp_gemm3_norm<<<128, 256, 0, stream>>>(h2, W3, b3, zout, zbf);
    contrast_partial<<<128, 256, 0, stream>>>(zbf, label, rws, s1ws, s0ws);
    loss_kernel<<<8, 256, 0, stream>>>(label, rws, s1ws, s0ws, zout + (out_size - 8));
}